// Round 1
// baseline (50.112 us; speedup 1.0000x reference)
//
#include <hip/hip_runtime.h>

// out[b,l,c,d] = p(c)*x0[d] + q(c)*x1[d]  (rank-2 outer product, see analysis)
//   p(c) = x0[c]*F[s0,s0] + x1[c]*F[s1,s0]
//   q(c) = x0[c]*F[s0,s1] + x1[c]*F[s1,s1]
//   s0 = 32-l, s1 = 33-l, F = filt[0][l]
//
// Layouts (row-major flat):
//   x:    (32, 1024, 2)          -> x[(b*1024 + c)*2 + ch]
//   filt: (1, 2, 64, 64)         -> filt[(l*64 + s)*64 + t]
//   out:  (32, 2, 1024, 1024)    -> out[((b*2 + l)*1024 + c)*1024 + d]
//
// Grid: one float4 store per thread; 32*2*1024*(1024/4) = 16,777,216 threads
// = 65536 blocks x 256. Within a block only d varies -> one contiguous 4KB
// row store per block; b,l,c are block-uniform.

__global__ __launch_bounds__(256) void filter_rank2_kernel(
    const float* __restrict__ x, const float* __restrict__ filt,
    float* __restrict__ out) {
  const long long idx = (long long)blockIdx.x * 256 + threadIdx.x;
  const int d4 = (int)(idx & 255);          // float4 index along d
  const int c  = (int)((idx >> 8) & 1023);
  const int l  = (int)((idx >> 18) & 1);
  const int b  = (int)(idx >> 19);

  const int s0 = 32 - l, s1 = 33 - l;
  const float* F = filt + l * 64 * 64;
  const float a00 = F[s0 * 64 + s0];
  const float a01 = F[s0 * 64 + s1];
  const float a10 = F[s1 * 64 + s0];
  const float a11 = F[s1 * 64 + s1];

  const float2* xb = (const float2*)(x + (long long)b * 2048);  // [c] -> (x0,x1)
  const float2 xc = xb[c];
  const float p = xc.x * a00 + xc.y * a10;
  const float q = xc.x * a01 + xc.y * a11;

  const int d0 = d4 * 4;
  // {x0[d0],x1[d0],x0[d0+1],x1[d0+1]} and the next pair — 32B-aligned loads
  const float4 xd01 = *(const float4*)(xb + d0);
  const float4 xd23 = *(const float4*)(xb + d0 + 2);

  float4 o;
  o.x = p * xd01.x + q * xd01.y;
  o.y = p * xd01.z + q * xd01.w;
  o.z = p * xd23.x + q * xd23.y;
  o.w = p * xd23.z + q * xd23.w;

  *(float4*)(out + idx * 4) = o;
}

extern "C" void kernel_launch(void* const* d_in, const int* in_sizes, int n_in,
                              void* d_out, int out_size, void* d_ws, size_t ws_size,
                              hipStream_t stream) {
  const float* x    = (const float*)d_in[0];
  const float* filt = (const float*)d_in[1];
  float* out        = (float*)d_out;

  // 32*2*1024*1024 outputs / 4 per thread / 256 threads per block
  const int blocks = 65536;
  filter_rank2_kernel<<<blocks, 256, 0, stream>>>(x, filt, out);
}